// Round 5
// baseline (130.029 us; speedup 1.0000x reference)
//
#include <hip/hip_runtime.h>
#include <hip/hip_bf16.h>
#include <math.h>

#define NN 1024

typedef short bf16x8 __attribute__((ext_vector_type(8)));
typedef float f32x4 __attribute__((ext_vector_type(4)));

__device__ __forceinline__ unsigned rne_u(float x) {
    unsigned u = __float_as_uint(x);
    return u + 0x7fffu + ((u >> 16) & 1u);
}
__device__ __forceinline__ float bf16_up_bits(unsigned hi16) {
    return __uint_as_float(hi16 << 16);
}
__device__ __forceinline__ unsigned pair_pack(float a, float b) {   // a->low, b->high, RNE
    return (rne_u(a) >> 16) | (rne_u(b) & 0xffff0000u);
}
// packed fp32x2 -> bf16x2 (v_cvt_pk_bf16_f32 on gfx950)
__device__ __forceinline__ unsigned pack2(float a, float b) {
    __hip_bfloat162 h = __float22bfloat162_rn(make_float2(a, b));
    unsigned u;
    __builtin_memcpy(&u, &h, 4);
    return u;
}

union U16 { uint4 u; bf16x8 v; };
union P4 { unsigned w[4]; bf16x8 v; };

// h1 fragment: relu(x + c) -> bf16 RNE, element e at k = q*8+e
__device__ __forceinline__ bf16x8 mk_frag(float4 x0, float4 x1, float4 c0, float4 c1) {
    P4 u;
    u.w[0] = pack2(fmaxf(x0.x + c0.x, 0.f), fmaxf(x0.y + c0.y, 0.f));
    u.w[1] = pack2(fmaxf(x0.z + c0.z, 0.f), fmaxf(x0.w + c0.w, 0.f));
    u.w[2] = pack2(fmaxf(x1.x + c1.x, 0.f), fmaxf(x1.y + c1.y, 0.f));
    u.w[3] = pack2(fmaxf(x1.z + c1.z, 0.f), fmaxf(x1.w + c1.w, 0.f));
    return u.v;
}

// ---- prep: blocks [0,512): A'=z_c@W1c+b1, B=z_d@W1d (fp32 exact).
//            blocks [512,514): W2 -> MFMA frag layout (hi+lo bf16), zero Srow.
__global__ void prep_kernel(const float* __restrict__ z_c, const float* __restrict__ z_d,
                            const float* __restrict__ W1, const float* __restrict__ b1,
                            const float* __restrict__ W2,
                            float* __restrict__ Ap, float* __restrict__ Bp,
                            uint4* __restrict__ W2hi, uint4* __restrict__ W2lo,
                            float* __restrict__ Srow) {
    if (blockIdx.x < 512) {
        int t = blockIdx.x * 256 + threadIdx.x;
        int sel = t >> 16;            // 0 -> A', 1 -> B
        int idx = t & 0xffff;
        int n = idx >> 6, h = idx & 63;
        const float* z = (sel ? z_d : z_c) + n * 64;
        const float* w = W1 + (sel ? 4096 : 0) + h;   // W1 (128,64) row-major
        float a0 = sel ? 0.f : b1[h], a1 = 0.f;
        #pragma unroll
        for (int k = 0; k < 64; k += 2) {
            a0 = fmaf(z[k],     w[k * 64],       a0);
            a1 = fmaf(z[k + 1], w[(k + 1) * 64], a1);
        }
        (sel ? Bp : Ap)[idx] = a0 + a1;
    } else {
        int tt = (blockIdx.x - 512) * 256 + threadIdx.x;   // 0..511
        Srow[tt] = 0.f; Srow[tt + 512] = 0.f;
        int f = tt >> 6, lane = tt & 63;                   // f = s*4 + t
        int s = f >> 2, t4 = f & 3, q = lane >> 4, l15 = lane & 15;
        int n = t4 * 16 + l15;
        unsigned hi[4], lo[4];
        #pragma unroll
        for (int p = 0; p < 4; ++p) {
            int k = s * 32 + q * 8 + 2 * p;
            float w0 = W2[k * 64 + n], w1 = W2[(k + 1) * 64 + n];
            unsigned h0 = rne_u(w0) >> 16, h1 = rne_u(w1) >> 16;
            hi[p] = h0 | (h1 << 16);
            lo[p] = pair_pack(w0 - bf16_up_bits(h0), w1 - bf16_up_bits(h1));
        }
        W2hi[f * 64 + lane] = make_uint4(hi[0], hi[1], hi[2], hi[3]);
        W2lo[f * 64 + lane] = make_uint4(lo[0], lo[1], lo[2], lo[3]);
    }
}

// ---- main: SINGLE-WAVE workgroups. 16384 blocks x 64 thr: block = (i, 16th of j).
// Each wave: 4 tiles of 16 j's. No LDS, no __syncthreads, no block-tail machinery.
// Operand-swapped MFMA (W2-frag as A, h1-frag as B): acc[t][r] =
// h2pre[j = jb + l15][h = t*16 + q*4 + r], acc initialized to b2.
// Diagonal T0[i]: exactly one writer -> plain store (no single-address atomic hotspot).
__global__ void __launch_bounds__(64)
main_kernel(const float* __restrict__ Ap, const float* __restrict__ Bp,
            const uint4* __restrict__ W2hi, const uint4* __restrict__ W2lo,
            const float* __restrict__ b2, const float* __restrict__ Wo,
            float* __restrict__ Srow, float* __restrict__ T0row) {
    const int i    = blockIdx.x >> 4;
    const int six  = blockIdx.x & 15;
    const int lane = threadIdx.x;        // 0..63, one wave
    const int l15  = lane & 15;
    const int q    = lane >> 4;

    // W2 fragments: 16 dwordx4 loads; 16 KB working set -> L1-resident per CU
    bf16x8 whi[2][4], wlo[2][4];
    #pragma unroll
    for (int f = 0; f < 8; ++f) {
        U16 a, b;
        a.u = W2hi[f * 64 + lane];
        b.u = W2lo[f * 64 + lane];
        whi[f >> 2][f & 3] = a.v;
        wlo[f >> 2][f & 3] = b.v;
    }

    // B_i per-lane slice, k = s*32 + q*8 + e
    const float* bpr = Bp + i * 64 + q * 8;
    float4 c00 = *(const float4*)(bpr);
    float4 c01 = *(const float4*)(bpr + 4);
    float4 c10 = *(const float4*)(bpr + 32);
    float4 c11 = *(const float4*)(bpr + 36);

    // b2 folded into acc init; Wo per-lane, element (t,r) is h = t*16 + q*4 + r
    f32x4 b2v[4];
    float wov[4][4];
    #pragma unroll
    for (int t = 0; t < 4; ++t) {
        float4 bt = *(const float4*)(b2 + t * 16 + q * 4);
        float4 wt = *(const float4*)(Wo + t * 16 + q * 4);
        b2v[t] = (f32x4){bt.x, bt.y, bt.z, bt.w};
        wov[t][0] = wt.x; wov[t][1] = wt.y; wov[t][2] = wt.z; wov[t][3] = wt.w;
    }

    const int jbase = six * 64;
    const float* ap = Ap + (jbase + l15) * 64 + q * 8;
    float4 x00 = *(const float4*)(ap);
    float4 x01 = *(const float4*)(ap + 4);
    float4 x10 = *(const float4*)(ap + 32);
    float4 x11 = *(const float4*)(ap + 36);

    float sacc = 0.f;

    #pragma unroll
    for (int tile = 0; tile < 4; ++tile) {
        bf16x8 a0 = mk_frag(x00, x01, c00, c01);   // k 0..31
        bf16x8 a1 = mk_frag(x10, x11, c10, c11);   // k 32..63
        if (tile < 3) {                             // prefetch next tile
            ap += 16 * 64;
            x00 = *(const float4*)(ap);
            x01 = *(const float4*)(ap + 4);
            x10 = *(const float4*)(ap + 32);
            x11 = *(const float4*)(ap + 36);
        }

        f32x4 acc[4];
        #pragma unroll
        for (int t = 0; t < 4; ++t) acc[t] = b2v[t];   // h2pre + b2 for free
        #pragma unroll
        for (int t = 0; t < 4; ++t) {
            acc[t] = __builtin_amdgcn_mfma_f32_16x16x32_bf16(whi[0][t], a0, acc[t], 0, 0, 0);
            acc[t] = __builtin_amdgcn_mfma_f32_16x16x32_bf16(whi[1][t], a1, acc[t], 0, 0, 0);
            acc[t] = __builtin_amdgcn_mfma_f32_16x16x32_bf16(wlo[0][t], a0, acc[t], 0, 0, 0);
            acc[t] = __builtin_amdgcn_mfma_f32_16x16x32_bf16(wlo[1][t], a1, acc[t], 0, 0, 0);
        }

        // T1[j] = sum_h relu(acc)*Wo: 4 parallel fmaf chains (depth 4) + tree
        float p0 = 0.f, p1 = 0.f, p2 = 0.f, p3 = 0.f;
        #pragma unroll
        for (int t = 0; t < 4; ++t) {
            p0 = fmaf(fmaxf(acc[t][0], 0.f), wov[t][0], p0);
            p1 = fmaf(fmaxf(acc[t][1], 0.f), wov[t][1], p1);
            p2 = fmaf(fmaxf(acc[t][2], 0.f), wov[t][2], p2);
            p3 = fmaf(fmaxf(acc[t][3], 0.f), wov[t][3], p3);
        }
        float psum = (p0 + p1) + (p2 + p3);
        psum += __shfl_xor(psum, 16);
        psum += __shfl_xor(psum, 32);   // T1[j], replicated over the 4 q-groups

        const int j = jbase + tile * 16 + l15;
        if (j == i && q == 0) T0row[i] = psum;   // diagonal: exactly one writer
        sacc += __expf(psum);
    }

    // reduce over the 16 l15 lanes only (q-groups are exact replicas -> no 4x factor)
    sacc += __shfl_xor(sacc, 1);
    sacc += __shfl_xor(sacc, 2);
    sacc += __shfl_xor(sacc, 4);
    sacc += __shfl_xor(sacc, 8);
    if (lane == 0) atomicAdd(&Srow[i], sacc);   // 16 adds per i, 1024 addresses
}

// ---- combine+finish: 1 block x 1024 thr.
// bound = mean(T0) - (mean(log Srow) - ln N)
__global__ void __launch_bounds__(1024)
combine_finish(const float* __restrict__ Srow, const float* __restrict__ T0row,
               float* __restrict__ out) {
    int i = threadIdx.x;
    float l  = logf(Srow[i]);
    float t0 = T0row[i];
    #pragma unroll
    for (int off = 1; off < 64; off <<= 1) {
        l  += __shfl_xor(l, off);
        t0 += __shfl_xor(t0, off);
    }
    __shared__ float sl[16], st[16];
    int w = threadIdx.x >> 6;
    if ((threadIdx.x & 63) == 0) { sl[w] = l; st[w] = t0; }
    __syncthreads();
    if (threadIdx.x == 0) {
        float L = 0.f, T = 0.f;
        #pragma unroll
        for (int k = 0; k < 16; ++k) { L += sl[k]; T += st[k]; }
        out[0] = (T - L) * (1.0f / 1024.0f) + 6.9314718055994531f;
    }
}

extern "C" void kernel_launch(void* const* d_in, const int* in_sizes, int n_in,
                              void* d_out, int out_size, void* d_ws, size_t ws_size,
                              hipStream_t stream) {
    const float* z_c = (const float*)d_in[0];
    const float* z_d = (const float*)d_in[1];
    const float* W1  = (const float*)d_in[2];
    const float* b1  = (const float*)d_in[3];
    const float* W2  = (const float*)d_in[4];
    const float* b2  = (const float*)d_in[5];
    const float* Wo  = (const float*)d_in[6];
    // d_in[7] = bo: shifts T0.mean and every LSE equally -> cancels; omitted.
    float* out   = (float*)d_out;

    float* Ap    = (float*)d_ws;                 // 65536 fp32
    float* Bp    = Ap + NN * 64;                 // 65536 fp32
    uint4* W2hi  = (uint4*)(Bp + NN * 64);       // 512 uint4 (8 KB)
    uint4* W2lo  = W2hi + 512;                   // 512 uint4 (8 KB)
    float* Srow  = (float*)(W2lo + 512);         // 1024 fp32
    float* T0row = Srow + NN;                    // 1024 fp32

    prep_kernel<<<514, 256, 0, stream>>>(z_c, z_d, W1, b1, W2, Ap, Bp, W2hi, W2lo, Srow);
    main_kernel<<<16384, 64, 0, stream>>>(Ap, Bp, W2hi, W2lo, b2, Wo, Srow, T0row);
    combine_finish<<<1, 1024, 0, stream>>>(Srow, T0row, out);
}